// Round 1
// baseline (317.898 us; speedup 1.0000x reference)
//
#include <hip/hip_runtime.h>

// ---------------------------------------------------------------------------
// Fused attention block, bf16 MFMA pipeline.
//   x[2,2048,1024] -> qkv GEMM (+bias, fused per-head LN on q,k) -> flash attn
//   -> proj GEMM (+bias) -> out fp32.
// MFMA 16x16x32 bf16 layouts (per guide / learn_hip verified):
//   A: lane l holds row (l&15), k = 8*(l>>4)+e (8 contiguous bf16)
//   B: lane l holds col (l&15), k = 8*(l>>4)+e
//   C/D: lane l holds col (l&15), row = (l>>4)*4 + reg
// ---------------------------------------------------------------------------

typedef short bf16x8 __attribute__((ext_vector_type(8)));
typedef float f32x4  __attribute__((ext_vector_type(4)));

__device__ __forceinline__ short f2bf(float f) {
  union { float f; unsigned u; } c; c.f = f;
  unsigned r = c.u + 0x7fffu + ((c.u >> 16) & 1u);   // RNE
  return (short)(r >> 16);
}

// global -> LDS direct copy, 16B per lane. LDS dest must be wave-uniform base;
// HW writes lane i at ldsbase + i*16. Cast through integers (addrspacecast via
// C-style pointer cast is rejected; low 32 bits of a generic LDS pointer are
// the LDS offset).
__device__ __forceinline__ void gld16(const void* g, void* l) {
  __builtin_amdgcn_global_load_lds(
      (const __attribute__((address_space(1))) unsigned int*)(unsigned long long)g,
      (__attribute__((address_space(3))) unsigned int*)(unsigned int)(unsigned long long)l,
      16, 0, 0);
}

// ---------------------------------------------------------------------------
// convert fp32 -> bf16, 4 elements / thread
__global__ void k_cvt(const float* __restrict__ in, short* __restrict__ out, int n) {
  int i = (blockIdx.x * blockDim.x + threadIdx.x) * 4;
  if (i < n) {
    float4 f = *(const float4*)(in + i);
    short4 s;
    s.x = f2bf(f.x); s.y = f2bf(f.y); s.z = f2bf(f.z); s.w = f2bf(f.w);
    *(short4*)(out + i) = s;
  }
}

// transpose + convert: in[R][C] fp32 -> out[C][R] bf16. 32x32 tiles, 32x8 block.
__global__ void k_transpose(const float* __restrict__ in, short* __restrict__ out,
                            int R, int C) {
  __shared__ float t[32][33];
  const int tx = threadIdx.x, ty = threadIdx.y;
  const int c0 = blockIdx.x * 32, r0 = blockIdx.y * 32;
#pragma unroll
  for (int i = 0; i < 4; i++)
    t[ty * 4 + i][tx] = in[(size_t)(r0 + ty * 4 + i) * C + c0 + tx];
  __syncthreads();
#pragma unroll
  for (int i = 0; i < 4; i++)
    out[(size_t)(c0 + ty * 4 + i) * R + r0 + tx] = f2bf(t[tx][ty * 4 + i]);
}

// ---------------------------------------------------------------------------
// GEMM mainloop (m97 structure): C128x128 = A[M,K]bf16 @ B[N,K]bf16^T.
// 256 threads = 4 waves in 2x2; each wave 64x64 = 4x4 frags; BK=64 (2 k-steps).
// Single-buffered LDS, global_load_lds width 16.
__device__ __forceinline__ void mm_loop(const short* __restrict__ A,
                                        const short* __restrict__ B,
                                        int K, int mBase, int nBase,
                                        short* As, short* Bs, f32x4 acc[4][4]) {
  const int tid = threadIdx.x;
  const int w = tid >> 6, lane = tid & 63;
  const int wr = w >> 1, wc = w & 1;
  const int lhi = lane >> 4, llo = lane & 15;
  const int rin = lane >> 3;            // row within 8-row chunk (8 lanes/row)
  const int kin = (lane & 7) * 8;       // k element offset within row

  const f32x4 fz = {0.f, 0.f, 0.f, 0.f};
#pragma unroll
  for (int mi = 0; mi < 4; mi++)
#pragma unroll
    for (int ni = 0; ni < 4; ni++) acc[mi][ni] = fz;

  const int nkt = K >> 6;
  for (int kb = 0; kb < nkt; kb++) {
    const int k0 = kb << 6;
#pragma unroll
    for (int i = 0; i < 4; i++) {                // 16 chunks of 1024B per matrix
      const int c = w * 4 + i;
      const int row = c * 8 + rin;
      gld16(A + (size_t)(mBase + row) * K + k0 + kin, As + c * 512);
      gld16(B + (size_t)(nBase + row) * K + k0 + kin, Bs + c * 512);
    }
    __syncthreads();                              // drains vmcnt
#pragma unroll
    for (int kk = 0; kk < 2; kk++) {
      bf16x8 a[4], b[4];
#pragma unroll
      for (int mi = 0; mi < 4; mi++)
        a[mi] = *(const bf16x8*)(As + (wr * 64 + mi * 16 + llo) * 64 + kk * 32 + lhi * 8);
#pragma unroll
      for (int ni = 0; ni < 4; ni++)
        b[ni] = *(const bf16x8*)(Bs + (wc * 64 + ni * 16 + llo) * 64 + kk * 32 + lhi * 8);
#pragma unroll
      for (int mi = 0; mi < 4; mi++)
#pragma unroll
        for (int ni = 0; ni < 4; ni++)
          acc[mi][ni] = __builtin_amdgcn_mfma_f32_16x16x32_bf16(a[mi], b[ni], acc[mi][ni], 0, 0, 0);
    }
    __syncthreads();
  }
}

// ---------------------------------------------------------------------------
// GEMM1: qkv = x @ w_qkv + b, fused per-head LN epilogue.
// Each wave's 64-col block is exactly one head of one of {q,k,v} (all col
// boundaries are multiples of 64). Writes Q,K as [bh][n][64], V as [bh][64][n].
__global__ __launch_bounds__(256) void k_gemm_qkv(
    const short* __restrict__ A, const short* __restrict__ B,
    const float* __restrict__ bqkv,
    const float* __restrict__ g_q, const float* __restrict__ be_q,
    const float* __restrict__ g_k, const float* __restrict__ be_k,
    short* __restrict__ Qg, short* __restrict__ Kg, short* __restrict__ Vtg) {
  __shared__ short As[128 * 64];
  __shared__ short Bs[128 * 64];
  f32x4 acc[4][4];
  const int mBase = blockIdx.x * 128, nBase = blockIdx.y * 128;
  mm_loop(A, B, 1024, mBase, nBase, As, Bs, acc);

  const int tid = threadIdx.x;
  const int w = tid >> 6, lane = tid & 63;
  const int wr = w >> 1, wc = w & 1;
  const int lhi = lane >> 4, llo = lane & 15;

  const int cg0 = nBase + wc * 64;       // multiple of 64
  const int t = cg0 >> 10;               // 0=q 1=k 2=v
  const int h = (cg0 & 1023) >> 6;

  float bias[4], gg[4], bb[4];
#pragma unroll
  for (int ni = 0; ni < 4; ni++) {
    const int d = ni * 16 + llo;
    bias[ni] = bqkv[cg0 + d];
    if (t == 0)      { gg[ni] = g_q[d]; bb[ni] = be_q[d]; }
    else if (t == 1) { gg[ni] = g_k[d]; bb[ni] = be_k[d]; }
    else             { gg[ni] = 1.f;    bb[ni] = 0.f; }
  }

#pragma unroll
  for (int mi = 0; mi < 4; mi++) {
    float v[4][4];
#pragma unroll
    for (int ni = 0; ni < 4; ni++)
#pragma unroll
      for (int j = 0; j < 4; j++) v[ni][j] = acc[mi][ni][j] + bias[ni];

    if (t < 2) {  // LayerNorm over the 64 cols of this head (per row)
#pragma unroll
      for (int j = 0; j < 4; j++) {
        float s = 0.f, s2 = 0.f;
#pragma unroll
        for (int ni = 0; ni < 4; ni++) { s += v[ni][j]; s2 += v[ni][j] * v[ni][j]; }
#pragma unroll
        for (int msk = 1; msk < 16; msk <<= 1) {
          s  += __shfl_xor(s,  msk, 64);
          s2 += __shfl_xor(s2, msk, 64);
        }
        const float mu = s * 0.015625f;
        const float var = s2 * 0.015625f - mu * mu;
        const float rs = rsqrtf(var + 1e-5f);
#pragma unroll
        for (int ni = 0; ni < 4; ni++) {
          float y = (v[ni][j] - mu) * rs * gg[ni] + bb[ni];
          if (t == 0) y *= 0.125f;       // hd^-0.5
          v[ni][j] = y;
        }
      }
    }
    const int rbase = mBase + wr * 64 + mi * 16 + lhi * 4;
#pragma unroll
    for (int j = 0; j < 4; j++) {
      const int r = rbase + j;
      const int b_ = r >> 11;            // batch
      const int n = r & 2047;
      const int bh = b_ * 16 + h;
#pragma unroll
      for (int ni = 0; ni < 4; ni++) {
        const int d = ni * 16 + llo;
        const short val = f2bf(v[ni][j]);
        if (t == 0)      Qg[((size_t)bh * 2048 + n) * 64 + d] = val;
        else if (t == 1) Kg[((size_t)bh * 2048 + n) * 64 + d] = val;
        else             Vtg[((size_t)bh * 64 + d) * 2048 + n] = val;
      }
    }
  }
}

// ---------------------------------------------------------------------------
// Flash attention. Block = (qb, bh): 64 q-rows, 4 waves x 16 rows.
// K tile [64 kr][64 d] and V tile transposed [64 d][64 kr] in LDS.
// Online softmax in fp32; P re-laid out through per-wave padded LDS.
__global__ __launch_bounds__(256) void k_attn(const short* __restrict__ Qg,
                                              const short* __restrict__ Kg,
                                              const short* __restrict__ Vtg,
                                              short* __restrict__ aout) {
  __shared__ short Ks[64 * 64];
  __shared__ short Vs[64 * 64];
  __shared__ short Ps[4 * 16 * 72];      // per-wave [16 rows][72] (pad 72 vs 64)
  const int tid = threadIdx.x;
  const int w = tid >> 6, lane = tid & 63;
  const int lhi = lane >> 4, llo = lane & 15;
  const int rin = lane >> 3, kin = (lane & 7) * 8;
  const int bh = blockIdx.y;
  const int qrow0 = blockIdx.x * 64 + w * 16;

  // Q fragments live in registers for the whole kernel (16 rows x 64 d)
  const short* Qrow = Qg + ((size_t)bh * 2048 + qrow0 + llo) * 64;
  const bf16x8 qa0 = *(const bf16x8*)(Qrow + lhi * 8);
  const bf16x8 qa1 = *(const bf16x8*)(Qrow + 32 + lhi * 8);

  const f32x4 fz = {0.f, 0.f, 0.f, 0.f};
  f32x4 o[4];
#pragma unroll
  for (int dg = 0; dg < 4; dg++) o[dg] = fz;
  float m_run[4], l_run[4];
#pragma unroll
  for (int j = 0; j < 4; j++) { m_run[j] = -1e30f; l_run[j] = 0.f; }

  short* Pw = Ps + w * 1152;

  for (int kt = 0; kt < 32; kt++) {
    const int kr0 = kt * 64;
#pragma unroll
    for (int i = 0; i < 4; i++) {        // 8 chunks K + 8 chunks V, 4 per wave
      const int cc = w * 4 + i;
      if (cc < 8) {
        gld16(Kg + ((size_t)bh * 2048 + kr0 + cc * 8 + rin) * 64 + kin, Ks + cc * 512);
      } else {
        const int c2 = cc - 8;
        gld16(Vtg + ((size_t)bh * 64 + c2 * 8 + rin) * 2048 + kr0 + kin, Vs + c2 * 512);
      }
    }
    __syncthreads();

    // S[16 x 64] = Q @ K^T
    f32x4 s[4];
#pragma unroll
    for (int krg = 0; krg < 4; krg++) {
      const bf16x8 kb0 = *(const bf16x8*)(Ks + (krg * 16 + llo) * 64 + lhi * 8);
      const bf16x8 kb1 = *(const bf16x8*)(Ks + (krg * 16 + llo) * 64 + 32 + lhi * 8);
      f32x4 z = fz;
      z = __builtin_amdgcn_mfma_f32_16x16x32_bf16(qa0, kb0, z, 0, 0, 0);
      z = __builtin_amdgcn_mfma_f32_16x16x32_bf16(qa1, kb1, z, 0, 0, 0);
      s[krg] = z;
    }

    // online softmax (lane holds rows lhi*4+j, cols krg*16+llo)
#pragma unroll
    for (int j = 0; j < 4; j++) {
      float mx = fmaxf(fmaxf(s[0][j], s[1][j]), fmaxf(s[2][j], s[3][j]));
#pragma unroll
      for (int msk = 1; msk < 16; msk <<= 1) mx = fmaxf(mx, __shfl_xor(mx, msk, 64));
      const float mn = fmaxf(m_run[j], mx);
      const float scale = __expf(m_run[j] - mn);
      m_run[j] = mn;
      float sm = 0.f;
#pragma unroll
      for (int krg = 0; krg < 4; krg++) {
        const float p = __expf(s[krg][j] - mn);
        s[krg][j] = p; sm += p;
      }
#pragma unroll
      for (int msk = 1; msk < 16; msk <<= 1) sm += __shfl_xor(sm, msk, 64);
      l_run[j] = l_run[j] * scale + sm;
#pragma unroll
      for (int dg = 0; dg < 4; dg++) o[dg][j] *= scale;
    }

    // P (C-layout) -> per-wave LDS -> A-layout fragments
#pragma unroll
    for (int krg = 0; krg < 4; krg++)
#pragma unroll
      for (int j = 0; j < 4; j++)
        Pw[(lhi * 4 + j) * 72 + krg * 16 + llo] = f2bf(s[krg][j]);

    const bf16x8 pa0 = *(const bf16x8*)(Pw + llo * 72 + lhi * 8);
    const bf16x8 pa1 = *(const bf16x8*)(Pw + llo * 72 + 32 + lhi * 8);

    // O += P @ V  (V^T in LDS so B-frag reads are contiguous)
#pragma unroll
    for (int dg = 0; dg < 4; dg++) {
      const bf16x8 vb0 = *(const bf16x8*)(Vs + (dg * 16 + llo) * 64 + lhi * 8);
      const bf16x8 vb1 = *(const bf16x8*)(Vs + (dg * 16 + llo) * 64 + 32 + lhi * 8);
      o[dg] = __builtin_amdgcn_mfma_f32_16x16x32_bf16(pa0, vb0, o[dg], 0, 0, 0);
      o[dg] = __builtin_amdgcn_mfma_f32_16x16x32_bf16(pa1, vb1, o[dg], 0, 0, 0);
    }
    __syncthreads();
  }

  const int b_ = bh >> 4, h = bh & 15;
#pragma unroll
  for (int j = 0; j < 4; j++) {
    const float inv = 1.f / l_run[j];
    const int n = qrow0 + lhi * 4 + j;
#pragma unroll
    for (int dg = 0; dg < 4; dg++)
      aout[((size_t)(b_ * 2048 + n)) * 1024 + h * 64 + dg * 16 + llo] = f2bf(o[dg][j] * inv);
  }
}

// ---------------------------------------------------------------------------
// GEMM2: out = aout @ w_proj + b_proj  (fp32 output)
__global__ __launch_bounds__(256) void k_gemm_proj(const short* __restrict__ A,
                                                   const short* __restrict__ B,
                                                   const float* __restrict__ bias,
                                                   float* __restrict__ C) {
  __shared__ short As[128 * 64];
  __shared__ short Bs[128 * 64];
  f32x4 acc[4][4];
  const int mBase = blockIdx.x * 128, nBase = blockIdx.y * 128;
  mm_loop(A, B, 1024, mBase, nBase, As, Bs, acc);

  const int tid = threadIdx.x;
  const int w = tid >> 6, lane = tid & 63;
  const int wr = w >> 1, wc = w & 1;
  const int lhi = lane >> 4, llo = lane & 15;
#pragma unroll
  for (int mi = 0; mi < 4; mi++)
#pragma unroll
    for (int ni = 0; ni < 4; ni++) {
      const int col = nBase + wc * 64 + ni * 16 + llo;
      const float bv = bias[col];
#pragma unroll
      for (int j = 0; j < 4; j++) {
        const int row = mBase + wr * 64 + mi * 16 + lhi * 4 + j;
        C[(size_t)row * 1024 + col] = acc[mi][ni][j] + bv;
      }
    }
}

// ---------------------------------------------------------------------------
extern "C" void kernel_launch(void* const* d_in, const int* in_sizes, int n_in,
                              void* d_out, int out_size, void* d_ws, size_t ws_size,
                              hipStream_t stream) {
  const float* x      = (const float*)d_in[0];
  const float* w_qkv  = (const float*)d_in[1];
  const float* b_qkv  = (const float*)d_in[2];
  const float* g_q    = (const float*)d_in[3];
  const float* be_q   = (const float*)d_in[4];
  const float* g_k    = (const float*)d_in[5];
  const float* be_k   = (const float*)d_in[6];
  const float* w_proj = (const float*)d_in[7];
  const float* b_proj = (const float*)d_in[8];
  float* out = (float*)d_out;

  char* ws = (char*)d_ws;
  short* xb     = (short*)(ws);                       // 4096x1024      8 MB
  short* wqkvT  = (short*)(ws + ((size_t)8  << 20));  // 3072x1024      6 MB
  short* wprojT = (short*)(ws + ((size_t)14 << 20));  // 1024x1024      2 MB
  short* Qg     = (short*)(ws + ((size_t)16 << 20));  // [32][2048][64] 8 MB
  short* Kg     = (short*)(ws + ((size_t)24 << 20));  // [32][2048][64] 8 MB
  short* Vtg    = (short*)(ws + ((size_t)32 << 20));  // [32][64][2048] 8 MB
  short* aout   = (short*)(ws + ((size_t)40 << 20));  // 4096x1024      8 MB

  k_cvt<<<4096, 256, 0, stream>>>(x, xb, 4096 * 1024);
  k_transpose<<<dim3(3072 / 32, 1024 / 32), dim3(32, 8), 0, stream>>>(w_qkv, wqkvT, 1024, 3072);
  k_transpose<<<dim3(1024 / 32, 1024 / 32), dim3(32, 8), 0, stream>>>(w_proj, wprojT, 1024, 1024);
  k_gemm_qkv<<<dim3(32, 24), 256, 0, stream>>>(xb, wqkvT, b_qkv, g_q, be_q, g_k, be_k, Qg, Kg, Vtg);
  k_attn<<<dim3(32, 32), 256, 0, stream>>>(Qg, Kg, Vtg, aout);
  k_gemm_proj<<<dim3(32, 8), 256, 0, stream>>>(aout, wprojT, b_proj, out);
}

// Round 3
// 234.514 us; speedup vs baseline: 1.3556x; 1.3556x over previous
//
#include <hip/hip_runtime.h>

// ---------------------------------------------------------------------------
// Fused attention block, bf16 MFMA pipeline.
//   x[2,2048,1024] -> qkv GEMM (+bias, fused per-head LN on q,k) -> flash attn
//   -> proj GEMM (+bias) -> out fp32.
// MFMA 16x16x32 bf16 layouts:
//   A: lane l holds row (l&15), k = 8*(l>>4)+e
//   B: lane l holds col (l&15), k = 8*(l>>4)+e
//   C/D: lane l holds col (l&15), row = (l>>4)*4 + reg
//
// k_attn notes:
//  * No softmax max-tracking: q is LN'd (norm 8) * 0.125, k is LN'd (norm 8)
//    => |S| <= 8, exp(S) <= e^8 ~ 3e3, row sums <= 6e6: fp32/bf16 safe.
//    Row sums computed by an extra MFMA with an all-ones B fragment.
//  * K/V/P LDS tiles XOR-swizzled to kill the 16-way bank conflicts of
//    128B-stride ds_read_b128. global_load_lds writes linearly, so the
//    swizzle is applied on the GLOBAL source address (involution) and on
//    the LDS read address.
//  * 2-phase double-buffered staging: stage(next) issued before compute(cur),
//    one __syncthreads() per K-tile (its vmcnt(0)+lgkmcnt(0) drain is the sync).
// ---------------------------------------------------------------------------

typedef short bf16x8 __attribute__((ext_vector_type(8)));
typedef float f32x4  __attribute__((ext_vector_type(4)));

__device__ __forceinline__ short f2bf(float f) {
  union { float f; unsigned u; } c; c.f = f;
  unsigned r = c.u + 0x7fffu + ((c.u >> 16) & 1u);   // RNE
  return (short)(r >> 16);
}

__device__ __forceinline__ void gld16(const void* g, void* l) {
  __builtin_amdgcn_global_load_lds(
      (const __attribute__((address_space(1))) unsigned int*)(unsigned long long)g,
      (__attribute__((address_space(3))) unsigned int*)(unsigned int)(unsigned long long)l,
      16, 0, 0);
}

// ---------------------------------------------------------------------------
__global__ void k_cvt(const float* __restrict__ in, short* __restrict__ out, int n) {
  int i = (blockIdx.x * blockDim.x + threadIdx.x) * 4;
  if (i < n) {
    float4 f = *(const float4*)(in + i);
    short4 s;
    s.x = f2bf(f.x); s.y = f2bf(f.y); s.z = f2bf(f.z); s.w = f2bf(f.w);
    *(short4*)(out + i) = s;
  }
}

__global__ void k_transpose(const float* __restrict__ in, short* __restrict__ out,
                            int R, int C) {
  __shared__ float t[32][33];
  const int tx = threadIdx.x, ty = threadIdx.y;
  const int c0 = blockIdx.x * 32, r0 = blockIdx.y * 32;
#pragma unroll
  for (int i = 0; i < 4; i++)
    t[ty * 4 + i][tx] = in[(size_t)(r0 + ty * 4 + i) * C + c0 + tx];
  __syncthreads();
#pragma unroll
  for (int i = 0; i < 4; i++)
    out[(size_t)(c0 + ty * 4 + i) * R + r0 + tx] = f2bf(t[tx][ty * 4 + i]);
}

// ---------------------------------------------------------------------------
// GEMM mainloop (m97 structure): C128x128 = A[M,K]bf16 @ B[N,K]bf16^T.
__device__ __forceinline__ void mm_loop(const short* __restrict__ A,
                                        const short* __restrict__ B,
                                        int K, int mBase, int nBase,
                                        short* As, short* Bs, f32x4 acc[4][4]) {
  const int tid = threadIdx.x;
  const int w = tid >> 6, lane = tid & 63;
  const int wr = w >> 1, wc = w & 1;
  const int lhi = lane >> 4, llo = lane & 15;
  const int rin = lane >> 3;
  const int kin = (lane & 7) * 8;

  const f32x4 fz = {0.f, 0.f, 0.f, 0.f};
#pragma unroll
  for (int mi = 0; mi < 4; mi++)
#pragma unroll
    for (int ni = 0; ni < 4; ni++) acc[mi][ni] = fz;

  const int nkt = K >> 6;
  for (int kb = 0; kb < nkt; kb++) {
    const int k0 = kb << 6;
#pragma unroll
    for (int i = 0; i < 4; i++) {
      const int c = w * 4 + i;
      const int row = c * 8 + rin;
      gld16(A + (size_t)(mBase + row) * K + k0 + kin, As + c * 512);
      gld16(B + (size_t)(nBase + row) * K + k0 + kin, Bs + c * 512);
    }
    __syncthreads();
#pragma unroll
    for (int kk = 0; kk < 2; kk++) {
      bf16x8 a[4], b[4];
#pragma unroll
      for (int mi = 0; mi < 4; mi++)
        a[mi] = *(const bf16x8*)(As + (wr * 64 + mi * 16 + llo) * 64 + kk * 32 + lhi * 8);
#pragma unroll
      for (int ni = 0; ni < 4; ni++)
        b[ni] = *(const bf16x8*)(Bs + (wc * 64 + ni * 16 + llo) * 64 + kk * 32 + lhi * 8);
#pragma unroll
      for (int mi = 0; mi < 4; mi++)
#pragma unroll
        for (int ni = 0; ni < 4; ni++)
          acc[mi][ni] = __builtin_amdgcn_mfma_f32_16x16x32_bf16(a[mi], b[ni], acc[mi][ni], 0, 0, 0);
    }
    __syncthreads();
  }
}

// ---------------------------------------------------------------------------
// GEMM1: qkv = x @ w_qkv + b, fused per-head LN epilogue.
__global__ __launch_bounds__(256) void k_gemm_qkv(
    const short* __restrict__ A, const short* __restrict__ B,
    const float* __restrict__ bqkv,
    const float* __restrict__ g_q, const float* __restrict__ be_q,
    const float* __restrict__ g_k, const float* __restrict__ be_k,
    short* __restrict__ Qg, short* __restrict__ Kg, short* __restrict__ Vtg) {
  __shared__ short As[128 * 64];
  __shared__ short Bs[128 * 64];
  f32x4 acc[4][4];
  const int mBase = blockIdx.x * 128, nBase = blockIdx.y * 128;
  mm_loop(A, B, 1024, mBase, nBase, As, Bs, acc);

  const int tid = threadIdx.x;
  const int w = tid >> 6, lane = tid & 63;
  const int wr = w >> 1, wc = w & 1;
  const int lhi = lane >> 4, llo = lane & 15;

  const int cg0 = nBase + wc * 64;
  const int t = cg0 >> 10;               // 0=q 1=k 2=v
  const int h = (cg0 & 1023) >> 6;

  float bias[4], gg[4], bb[4];
#pragma unroll
  for (int ni = 0; ni < 4; ni++) {
    const int d = ni * 16 + llo;
    bias[ni] = bqkv[cg0 + d];
    if (t == 0)      { gg[ni] = g_q[d]; bb[ni] = be_q[d]; }
    else if (t == 1) { gg[ni] = g_k[d]; bb[ni] = be_k[d]; }
    else             { gg[ni] = 1.f;    bb[ni] = 0.f; }
  }

#pragma unroll
  for (int mi = 0; mi < 4; mi++) {
    float v[4][4];
#pragma unroll
    for (int ni = 0; ni < 4; ni++)
#pragma unroll
      for (int j = 0; j < 4; j++) v[ni][j] = acc[mi][ni][j] + bias[ni];

    if (t < 2) {
#pragma unroll
      for (int j = 0; j < 4; j++) {
        float s = 0.f, s2 = 0.f;
#pragma unroll
        for (int ni = 0; ni < 4; ni++) { s += v[ni][j]; s2 += v[ni][j] * v[ni][j]; }
#pragma unroll
        for (int msk = 1; msk < 16; msk <<= 1) {
          s  += __shfl_xor(s,  msk, 64);
          s2 += __shfl_xor(s2, msk, 64);
        }
        const float mu = s * 0.015625f;
        const float var = s2 * 0.015625f - mu * mu;
        const float rs = rsqrtf(var + 1e-5f);
#pragma unroll
        for (int ni = 0; ni < 4; ni++) {
          float y = (v[ni][j] - mu) * rs * gg[ni] + bb[ni];
          if (t == 0) y *= 0.125f;
          v[ni][j] = y;
        }
      }
    }
    const int rbase = mBase + wr * 64 + mi * 16 + lhi * 4;
#pragma unroll
    for (int j = 0; j < 4; j++) {
      const int r = rbase + j;
      const int b_ = r >> 11;
      const int n = r & 2047;
      const int bh = b_ * 16 + h;
#pragma unroll
      for (int ni = 0; ni < 4; ni++) {
        const int d = ni * 16 + llo;
        const short val = f2bf(v[ni][j]);
        if (t == 0)      Qg[((size_t)bh * 2048 + n) * 64 + d] = val;
        else if (t == 1) Kg[((size_t)bh * 2048 + n) * 64 + d] = val;
        else             Vtg[((size_t)bh * 64 + d) * 2048 + n] = val;
      }
    }
  }
}

// ---------------------------------------------------------------------------
// Flash attention (no-max softmax, swizzled LDS, 2-phase dbuf staging).
__global__ __launch_bounds__(256) void k_attn(const short* __restrict__ Qg,
                                              const short* __restrict__ Kg,
                                              const short* __restrict__ Vtg,
                                              short* __restrict__ aout) {
  __shared__ short Ks[2][4096];     // [buf][64 rows][64 d], swizzled 16B slots
  __shared__ short Vs[2][4096];     // [buf][64 d][64 kr], swizzled
  __shared__ short Ps[4][1024];     // per-wave [16 q][64 k], swizzled
  const int tid = threadIdx.x;
  const int w = tid >> 6, lane = tid & 63;
  const int lhi = lane >> 4, llo = lane & 15;
  const int rin = lane >> 3;               // 0..7: row within 8-row chunk
  const int tg = (lane & 7) ^ rin;         // pre-swizzled 16B slot in source
  const int bh = blockIdx.y;
  const int qrow0 = blockIdx.x * 64 + w * 16;

  const short* Qrow = Qg + ((size_t)bh * 2048 + qrow0 + llo) * 64;
  const bf16x8 qa0 = *(const bf16x8*)(Qrow + lhi * 8);
  const bf16x8 qa1 = *(const bf16x8*)(Qrow + 32 + lhi * 8);

  bf16x8 onesb;
#pragma unroll
  for (int e = 0; e < 8; e++) onesb[e] = (short)0x3F80;   // bf16 1.0

  const f32x4 fz = {0.f, 0.f, 0.f, 0.f};
  f32x4 o[4];
#pragma unroll
  for (int dg = 0; dg < 4; dg++) o[dg] = fz;
  f32x4 lsum = fz;

  short* Pw = Ps[w];
  const size_t kbase = (size_t)bh * 2048;
  const size_t vbase = (size_t)bh * 64;

#define STAGE(buf, kt_)                                                        \
  {                                                                            \
    const int kr0_ = (kt_) * 64;                                               \
    _Pragma("unroll")                                                          \
    for (int i = 0; i < 4; i++) {                                              \
      const int cc = w * 4 + i;                                                \
      if (cc < 8) {                                                            \
        gld16(Kg + (kbase + kr0_ + cc * 8 + rin) * 64 + tg * 8,                \
              &Ks[buf][cc * 512]);                                             \
      } else {                                                                 \
        const int c2 = cc - 8;                                                 \
        gld16(Vtg + (vbase + c2 * 8 + rin) * 2048 + kr0_ + tg * 8,             \
              &Vs[buf][c2 * 512]);                                             \
      }                                                                        \
    }                                                                          \
  }

  STAGE(0, 0);
  __syncthreads();
  int cur = 0;

  for (int kt = 0; kt < 32; kt++) {
    if (kt < 31) STAGE(cur ^ 1, kt + 1);

    const short* Kc = Ks[cur];
    const short* Vc = Vs[cur];

    // S[16 x 64] = Q @ K^T   (K rows swizzle-read)
    f32x4 s[4];
#pragma unroll
    for (int krg = 0; krg < 4; krg++) {
      const int rk = krg * 16 + llo;
      const int sw = rk & 7;
      const bf16x8 kb0 = *(const bf16x8*)(Kc + rk * 64 + ((lhi ^ sw)) * 8);
      const bf16x8 kb1 = *(const bf16x8*)(Kc + rk * 64 + (((4 + lhi) ^ sw)) * 8);
      f32x4 z = fz;
      z = __builtin_amdgcn_mfma_f32_16x16x32_bf16(qa0, kb0, z, 0, 0, 0);
      z = __builtin_amdgcn_mfma_f32_16x16x32_bf16(qa1, kb1, z, 0, 0, 0);
      s[krg] = z;
    }

    // P = exp(S)  (|S|<=8 by construction; no max subtraction needed)
#pragma unroll
    for (int krg = 0; krg < 4; krg++)
#pragma unroll
      for (int j = 0; j < 4; j++) {
        const float p = __expf(s[krg][j]);
        const int row = lhi * 4 + j;
        const int slot = (krg * 2 + (llo >> 3)) ^ (row & 7);
        Pw[row * 64 + slot * 8 + (llo & 7)] = f2bf(p);
      }

    // P fragments (A-layout): row=llo, swizzle-read
    const int swp = llo & 7;
    const bf16x8 pa0 = *(const bf16x8*)(Pw + llo * 64 + ((lhi ^ swp)) * 8);
    const bf16x8 pa1 = *(const bf16x8*)(Pw + llo * 64 + (((4 + lhi) ^ swp)) * 8);

    // row sums via MFMA with ones-B (each col of C gets the full row sum)
    lsum = __builtin_amdgcn_mfma_f32_16x16x32_bf16(pa0, onesb, lsum, 0, 0, 0);
    lsum = __builtin_amdgcn_mfma_f32_16x16x32_bf16(pa1, onesb, lsum, 0, 0, 0);

    // O += P @ V   (V^T tile, swizzle-read)
#pragma unroll
    for (int dg = 0; dg < 4; dg++) {
      const int rv = dg * 16 + llo;
      const int swv = rv & 7;
      const bf16x8 vb0 = *(const bf16x8*)(Vc + rv * 64 + ((lhi ^ swv)) * 8);
      const bf16x8 vb1 = *(const bf16x8*)(Vc + rv * 64 + (((4 + lhi) ^ swv)) * 8);
      o[dg] = __builtin_amdgcn_mfma_f32_16x16x32_bf16(pa0, vb0, o[dg], 0, 0, 0);
      o[dg] = __builtin_amdgcn_mfma_f32_16x16x32_bf16(pa1, vb1, o[dg], 0, 0, 0);
    }
    __syncthreads();
    cur ^= 1;
  }
#undef STAGE

  const int b_ = bh >> 4, h = bh & 15;
#pragma unroll
  for (int j = 0; j < 4; j++) {
    const float inv = 1.f / lsum[j];
    const int n = qrow0 + lhi * 4 + j;
#pragma unroll
    for (int dg = 0; dg < 4; dg++)
      aout[((size_t)(b_ * 2048 + n)) * 1024 + h * 64 + dg * 16 + llo] = f2bf(o[dg][j] * inv);
  }
}

// ---------------------------------------------------------------------------
// GEMM2: out = aout @ w_proj + b_proj  (fp32 output)
__global__ __launch_bounds__(256) void k_gemm_proj(const short* __restrict__ A,
                                                   const short* __restrict__ B,
                                                   const float* __restrict__ bias,
                                                   float* __restrict__ C) {
  __shared__ short As[128 * 64];
  __shared__ short Bs[128 * 64];
  f32x4 acc[4][4];
  const int mBase = blockIdx.x * 128, nBase = blockIdx.y * 128;
  mm_loop(A, B, 1024, mBase, nBase, As, Bs, acc);

  const int tid = threadIdx.x;
  const int w = tid >> 6, lane = tid & 63;
  const int wr = w >> 1, wc = w & 1;
  const int lhi = lane >> 4, llo = lane & 15;
#pragma unroll
  for (int mi = 0; mi < 4; mi++)
#pragma unroll
    for (int ni = 0; ni < 4; ni++) {
      const int col = nBase + wc * 64 + ni * 16 + llo;
      const float bv = bias[col];
#pragma unroll
      for (int j = 0; j < 4; j++) {
        const int row = mBase + wr * 64 + mi * 16 + lhi * 4 + j;
        C[(size_t)row * 1024 + col] = acc[mi][ni][j] + bv;
      }
    }
}

// ---------------------------------------------------------------------------
extern "C" void kernel_launch(void* const* d_in, const int* in_sizes, int n_in,
                              void* d_out, int out_size, void* d_ws, size_t ws_size,
                              hipStream_t stream) {
  const float* x      = (const float*)d_in[0];
  const float* w_qkv  = (const float*)d_in[1];
  const float* b_qkv  = (const float*)d_in[2];
  const float* g_q    = (const float*)d_in[3];
  const float* be_q   = (const float*)d_in[4];
  const float* g_k    = (const float*)d_in[5];
  const float* be_k   = (const float*)d_in[6];
  const float* w_proj = (const float*)d_in[7];
  const float* b_proj = (const float*)d_in[8];
  float* out = (float*)d_out;

  char* ws = (char*)d_ws;
  short* xb     = (short*)(ws);                       // 4096x1024      8 MB
  short* wqkvT  = (short*)(ws + ((size_t)8  << 20));  // 3072x1024      6 MB
  short* wprojT = (short*)(ws + ((size_t)14 << 20));  // 1024x1024      2 MB
  short* Qg     = (short*)(ws + ((size_t)16 << 20));  // [32][2048][64] 8 MB
  short* Kg     = (short*)(ws + ((size_t)24 << 20));  // [32][2048][64] 8 MB
  short* Vtg    = (short*)(ws + ((size_t)32 << 20));  // [32][64][2048] 8 MB
  short* aout   = (short*)(ws + ((size_t)40 << 20));  // 4096x1024      8 MB

  k_cvt<<<4096, 256, 0, stream>>>(x, xb, 4096 * 1024);
  k_transpose<<<dim3(3072 / 32, 1024 / 32), dim3(32, 8), 0, stream>>>(w_qkv, wqkvT, 1024, 3072);
  k_transpose<<<dim3(1024 / 32, 1024 / 32), dim3(32, 8), 0, stream>>>(w_proj, wprojT, 1024, 1024);
  k_gemm_qkv<<<dim3(32, 24), 256, 0, stream>>>(xb, wqkvT, b_qkv, g_q, be_q, g_k, be_k, Qg, Kg, Vtg);
  k_attn<<<dim3(32, 32), 256, 0, stream>>>(Qg, Kg, Vtg, aout);
  k_gemm_proj<<<dim3(32, 8), 256, 0, stream>>>(aout, wprojT, b_proj, out);
}

// Round 5
// 220.133 us; speedup vs baseline: 1.4441x; 1.0653x over previous
//
#include <hip/hip_runtime.h>

// ---------------------------------------------------------------------------
// Fused attention block, bf16 MFMA pipeline.
//   x[2,2048,1024] -> qkv GEMM (+bias, fused per-head LN on q,k) -> flash attn
//   -> proj GEMM (+bias) -> out fp32.
// MFMA 16x16x32 bf16 layouts:
//   A: lane l holds row (l&15), k = 8*(l>>4)+e
//   B: lane l holds col (l&15), k = 8*(l>>4)+e
//   C/D: lane l holds col (l&15), row = (l>>4)*4 + reg
//
// k_attn notes:
//  * No softmax max-tracking: q is LN'd (unit norm after *hd^-0.5), k LN'd
//    (norm 8) => |S| <= 8 (Cauchy-Schwarz), exp(S) <= e^8 ~ 3e3, row sums
//    <= 6e6: fp32/bf16 safe. Row sums via MFMA with ones-B fragment.
//  * Swapped QK^T: mfma(K,Q) gives S^T in C-layout => lane holds 4
//    consecutive k for one q-row => P pair-packed in registers (verified
//    f2bf RNE) + ds_write_b64 (replaces 16 scalar b16 stores).
//    NOTE (R4 post-mortem): v_cvt_pk_bf16_f32 inline-asm for this pack
//    produced 10x absmax inflation (suspected operand-order/rounding) —
//    reverted to f2bf; do not reintroduce without an A/B refcheck.
//  * K/V/P LDS tiles XOR-swizzled (16B-slot ^ (row&7)); global_load_lds
//    writes linearly so the swizzle is pre-applied on the global source.
//  * 2-phase double-buffered staging, one __syncthreads() per K-tile.
// ---------------------------------------------------------------------------

typedef short bf16x8 __attribute__((ext_vector_type(8)));
typedef float f32x4  __attribute__((ext_vector_type(4)));

__device__ __forceinline__ short f2bf(float f) {
  union { float f; unsigned u; } c; c.f = f;
  unsigned r = c.u + 0x7fffu + ((c.u >> 16) & 1u);   // RNE
  return (short)(r >> 16);
}

__device__ __forceinline__ void gld16(const void* g, void* l) {
  __builtin_amdgcn_global_load_lds(
      (const __attribute__((address_space(1))) unsigned int*)(unsigned long long)g,
      (__attribute__((address_space(3))) unsigned int*)(unsigned int)(unsigned long long)l,
      16, 0, 0);
}

// ---------------------------------------------------------------------------
__global__ void k_cvt(const float* __restrict__ in, short* __restrict__ out, int n) {
  int i = (blockIdx.x * blockDim.x + threadIdx.x) * 4;
  if (i < n) {
    float4 f = *(const float4*)(in + i);
    short4 s;
    s.x = f2bf(f.x); s.y = f2bf(f.y); s.z = f2bf(f.z); s.w = f2bf(f.w);
    *(short4*)(out + i) = s;
  }
}

__global__ void k_transpose(const float* __restrict__ in, short* __restrict__ out,
                            int R, int C) {
  __shared__ float t[32][33];
  const int tx = threadIdx.x, ty = threadIdx.y;
  const int c0 = blockIdx.x * 32, r0 = blockIdx.y * 32;
#pragma unroll
  for (int i = 0; i < 4; i++)
    t[ty * 4 + i][tx] = in[(size_t)(r0 + ty * 4 + i) * C + c0 + tx];
  __syncthreads();
#pragma unroll
  for (int i = 0; i < 4; i++)
    out[(size_t)(c0 + ty * 4 + i) * R + r0 + tx] = f2bf(t[tx][ty * 4 + i]);
}

// ---------------------------------------------------------------------------
// GEMM mainloop: C128x128 = A[M,K]bf16 @ B[N,K]bf16^T.
// 2-phase double-buffered: STAGE(next) issued before compute(cur), one
// barrier per K-tile (its vmcnt(0)+lgkmcnt(0) drain is the sync).
__device__ __forceinline__ void mm_loop(const short* __restrict__ A,
                                        const short* __restrict__ B,
                                        int K, int mBase, int nBase,
                                        short* As, short* Bs, f32x4 acc[4][4]) {
  const int tid = threadIdx.x;
  const int w = tid >> 6, lane = tid & 63;
  const int wr = w >> 1, wc = w & 1;
  const int lhi = lane >> 4, llo = lane & 15;
  const int rin = lane >> 3;
  const int kin = (lane & 7) * 8;

  const f32x4 fz = {0.f, 0.f, 0.f, 0.f};
#pragma unroll
  for (int mi = 0; mi < 4; mi++)
#pragma unroll
    for (int ni = 0; ni < 4; ni++) acc[mi][ni] = fz;

  const int nkt = K >> 6;

#define MMSTAGE(buf, kb_)                                                      \
  {                                                                            \
    const int k0_ = (kb_) << 6;                                                \
    _Pragma("unroll")                                                          \
    for (int i = 0; i < 4; i++) {                                              \
      const int c = w * 4 + i;                                                 \
      const int row = c * 8 + rin;                                             \
      gld16(A + (size_t)(mBase + row) * K + k0_ + kin, As + (buf) * 8192 + c * 512); \
      gld16(B + (size_t)(nBase + row) * K + k0_ + kin, Bs + (buf) * 8192 + c * 512); \
    }                                                                          \
  }

  MMSTAGE(0, 0);
  __syncthreads();
  int cur = 0;

  for (int kb = 0; kb < nkt; kb++) {
    if (kb + 1 < nkt) MMSTAGE(cur ^ 1, kb + 1);
    const short* Ac = As + cur * 8192;
    const short* Bc = Bs + cur * 8192;
#pragma unroll
    for (int kk = 0; kk < 2; kk++) {
      bf16x8 a[4], b[4];
#pragma unroll
      for (int mi = 0; mi < 4; mi++)
        a[mi] = *(const bf16x8*)(Ac + (wr * 64 + mi * 16 + llo) * 64 + kk * 32 + lhi * 8);
#pragma unroll
      for (int ni = 0; ni < 4; ni++)
        b[ni] = *(const bf16x8*)(Bc + (wc * 64 + ni * 16 + llo) * 64 + kk * 32 + lhi * 8);
#pragma unroll
      for (int mi = 0; mi < 4; mi++)
#pragma unroll
        for (int ni = 0; ni < 4; ni++)
          acc[mi][ni] = __builtin_amdgcn_mfma_f32_16x16x32_bf16(a[mi], b[ni], acc[mi][ni], 0, 0, 0);
    }
    __syncthreads();
    cur ^= 1;
  }
#undef MMSTAGE
}

// ---------------------------------------------------------------------------
// GEMM1: qkv = x @ w_qkv + b, fused per-head LN epilogue.
__global__ __launch_bounds__(256) void k_gemm_qkv(
    const short* __restrict__ A, const short* __restrict__ B,
    const float* __restrict__ bqkv,
    const float* __restrict__ g_q, const float* __restrict__ be_q,
    const float* __restrict__ g_k, const float* __restrict__ be_k,
    short* __restrict__ Qg, short* __restrict__ Kg, short* __restrict__ Vtg) {
  __shared__ short As[2 * 8192];
  __shared__ short Bs[2 * 8192];
  f32x4 acc[4][4];
  const int mBase = blockIdx.x * 128, nBase = blockIdx.y * 128;
  mm_loop(A, B, 1024, mBase, nBase, As, Bs, acc);

  const int tid = threadIdx.x;
  const int w = tid >> 6, lane = tid & 63;
  const int wr = w >> 1, wc = w & 1;
  const int lhi = lane >> 4, llo = lane & 15;

  const int cg0 = nBase + wc * 64;
  const int t = cg0 >> 10;               // 0=q 1=k 2=v
  const int h = (cg0 & 1023) >> 6;

  float bias[4], gg[4], bb[4];
#pragma unroll
  for (int ni = 0; ni < 4; ni++) {
    const int d = ni * 16 + llo;
    bias[ni] = bqkv[cg0 + d];
    if (t == 0)      { gg[ni] = g_q[d]; bb[ni] = be_q[d]; }
    else if (t == 1) { gg[ni] = g_k[d]; bb[ni] = be_k[d]; }
    else             { gg[ni] = 1.f;    bb[ni] = 0.f; }
  }

#pragma unroll
  for (int mi = 0; mi < 4; mi++) {
    float v[4][4];
#pragma unroll
    for (int ni = 0; ni < 4; ni++)
#pragma unroll
      for (int j = 0; j < 4; j++) v[ni][j] = acc[mi][ni][j] + bias[ni];

    if (t < 2) {
#pragma unroll
      for (int j = 0; j < 4; j++) {
        float s = 0.f, s2 = 0.f;
#pragma unroll
        for (int ni = 0; ni < 4; ni++) { s += v[ni][j]; s2 += v[ni][j] * v[ni][j]; }
#pragma unroll
        for (int msk = 1; msk < 16; msk <<= 1) {
          s  += __shfl_xor(s,  msk, 64);
          s2 += __shfl_xor(s2, msk, 64);
        }
        const float mu = s * 0.015625f;
        const float var = s2 * 0.015625f - mu * mu;
        const float rs = rsqrtf(var + 1e-5f);
#pragma unroll
        for (int ni = 0; ni < 4; ni++) {
          float y = (v[ni][j] - mu) * rs * gg[ni] + bb[ni];
          if (t == 0) y *= 0.125f;       // hd^-0.5
          v[ni][j] = y;
        }
      }
    }
    const int rbase = mBase + wr * 64 + mi * 16 + lhi * 4;
#pragma unroll
    for (int j = 0; j < 4; j++) {
      const int r = rbase + j;
      const int b_ = r >> 11;
      const int n = r & 2047;
      const int bh = b_ * 16 + h;
#pragma unroll
      for (int ni = 0; ni < 4; ni++) {
        const int d = ni * 16 + llo;
        const short val = f2bf(v[ni][j]);
        if (t == 0)      Qg[((size_t)bh * 2048 + n) * 64 + d] = val;
        else if (t == 1) Kg[((size_t)bh * 2048 + n) * 64 + d] = val;
        else             Vtg[((size_t)bh * 64 + d) * 2048 + n] = val;
      }
    }
  }
}

// ---------------------------------------------------------------------------
// Flash attention: swapped QK^T, no-max softmax (__expf), packed b64 P-store,
// swizzled LDS, 2-phase dbuf staging, setprio around MFMA clusters.
__global__ __launch_bounds__(256) void k_attn(const short* __restrict__ Qg,
                                              const short* __restrict__ Kg,
                                              const short* __restrict__ Vtg,
                                              short* __restrict__ aout) {
  __shared__ short Ks[2][4096];     // [buf][64 rows][64 d], swizzled 16B slots
  __shared__ short Vs[2][4096];     // [buf][64 d][64 kr], swizzled
  __shared__ short Ps[4][1024];     // per-wave [16 q][64 k], swizzled
  const int tid = threadIdx.x;
  const int w = tid >> 6, lane = tid & 63;
  const int lhi = lane >> 4, llo = lane & 15;
  const int rin = lane >> 3;               // 0..7: row within 8-row chunk
  const int tg = (lane & 7) ^ rin;         // pre-swizzled 16B slot in source
  const int bh = blockIdx.y;
  const int qrow0 = blockIdx.x * 64 + w * 16;

  const short* Qrow = Qg + ((size_t)bh * 2048 + qrow0 + llo) * 64;
  const bf16x8 qa0 = *(const bf16x8*)(Qrow + lhi * 8);
  const bf16x8 qa1 = *(const bf16x8*)(Qrow + 32 + lhi * 8);

  bf16x8 onesb;
#pragma unroll
  for (int e = 0; e < 8; e++) onesb[e] = (short)0x3F80;   // bf16 1.0

  const f32x4 fz = {0.f, 0.f, 0.f, 0.f};
  f32x4 o[4];
#pragma unroll
  for (int dg = 0; dg < 4; dg++) o[dg] = fz;
  f32x4 lsum = fz;

  short* Pw = Ps[w];
  const size_t kbase = (size_t)bh * 2048;
  const size_t vbase = (size_t)bh * 64;

#define STAGE(buf, kt_)                                                        \
  {                                                                            \
    const int kr0_ = (kt_) * 64;                                               \
    _Pragma("unroll")                                                          \
    for (int i = 0; i < 4; i++) {                                              \
      const int cc = w * 4 + i;                                                \
      if (cc < 8) {                                                            \
        gld16(Kg + (kbase + kr0_ + cc * 8 + rin) * 64 + tg * 8,                \
              &Ks[buf][cc * 512]);                                             \
      } else {                                                                 \
        const int c2 = cc - 8;                                                 \
        gld16(Vtg + (vbase + c2 * 8 + rin) * 2048 + kr0_ + tg * 8,             \
              &Vs[buf][c2 * 512]);                                             \
      }                                                                        \
    }                                                                          \
  }

  STAGE(0, 0);
  __syncthreads();
  int cur = 0;

  for (int kt = 0; kt < 32; kt++) {
    if (kt < 31) STAGE(cur ^ 1, kt + 1);

    const short* Kc = Ks[cur];
    const short* Vc = Vs[cur];

    // S^T[64 k x 16 q] = K @ Q^T  (swapped operands; frag layouts identical)
    // => lane holds S[q=llo][k = krg*16 + lhi*4 + j]
    f32x4 s[4];
    __builtin_amdgcn_s_setprio(1);
#pragma unroll
    for (int krg = 0; krg < 4; krg++) {
      const int rk = krg * 16 + llo;
      const int sw = rk & 7;
      const bf16x8 kb0 = *(const bf16x8*)(Kc + rk * 64 + ((lhi ^ sw)) * 8);
      const bf16x8 kb1 = *(const bf16x8*)(Kc + rk * 64 + (((4 + lhi) ^ sw)) * 8);
      f32x4 z = fz;
      z = __builtin_amdgcn_mfma_f32_16x16x32_bf16(kb0, qa0, z, 0, 0, 0);
      z = __builtin_amdgcn_mfma_f32_16x16x32_bf16(kb1, qa1, z, 0, 0, 0);
      s[krg] = z;
    }
    __builtin_amdgcn_s_setprio(0);

    // P = exp(S); pack 4 consecutive-k bf16 via verified f2bf, one
    // ds_write_b64 per krg into the swizzled P tile.
#pragma unroll
    for (int krg = 0; krg < 4; krg++) {
      const float p0 = __expf(s[krg][0]);
      const float p1 = __expf(s[krg][1]);
      const float p2 = __expf(s[krg][2]);
      const float p3 = __expf(s[krg][3]);
      const unsigned u0 = (unsigned)(unsigned short)f2bf(p0) |
                          ((unsigned)(unsigned short)f2bf(p1) << 16);
      const unsigned u1 = (unsigned)(unsigned short)f2bf(p2) |
                          ((unsigned)(unsigned short)f2bf(p3) << 16);
      // byte addr: row llo, k = krg*16 + lhi*4 ; slot = k>>3, swizzled
      char* pb = (char*)Pw + llo * 128 +
                 (((krg * 2 + (lhi >> 1)) ^ (llo & 7)) << 4) + ((lhi & 1) << 3);
      *(uint2*)pb = make_uint2(u0, u1);
    }

    // P fragments (A-layout): row=llo, swizzle-read
    const int swp = llo & 7;
    const bf16x8 pa0 = *(const bf16x8*)(Pw + llo * 64 + ((lhi ^ swp)) * 8);
    const bf16x8 pa1 = *(const bf16x8*)(Pw + llo * 64 + (((4 + lhi) ^ swp)) * 8);

    __builtin_amdgcn_s_setprio(1);
    // row sums via MFMA with ones-B (each col of C gets the full row sum)
    lsum = __builtin_amdgcn_mfma_f32_16x16x32_bf16(pa0, onesb, lsum, 0, 0, 0);
    lsum = __builtin_amdgcn_mfma_f32_16x16x32_bf16(pa1, onesb, lsum, 0, 0, 0);

    // O += P @ V   (V^T tile, swizzle-read)
#pragma unroll
    for (int dg = 0; dg < 4; dg++) {
      const int rv = dg * 16 + llo;
      const int swv = rv & 7;
      const bf16x8 vb0 = *(const bf16x8*)(Vc + rv * 64 + ((lhi ^ swv)) * 8);
      const bf16x8 vb1 = *(const bf16x8*)(Vc + rv * 64 + (((4 + lhi) ^ swv)) * 8);
      o[dg] = __builtin_amdgcn_mfma_f32_16x16x32_bf16(pa0, vb0, o[dg], 0, 0, 0);
      o[dg] = __builtin_amdgcn_mfma_f32_16x16x32_bf16(pa1, vb1, o[dg], 0, 0, 0);
    }
    __builtin_amdgcn_s_setprio(0);
    __syncthreads();
    cur ^= 1;
  }
#undef STAGE

  const int b_ = bh >> 4, h = bh & 15;
#pragma unroll
  for (int j = 0; j < 4; j++) {
    const float inv = 1.f / lsum[j];
    const int n = qrow0 + lhi * 4 + j;
#pragma unroll
    for (int dg = 0; dg < 4; dg++)
      aout[((size_t)(b_ * 2048 + n)) * 1024 + h * 64 + dg * 16 + llo] = f2bf(o[dg][j] * inv);
  }
}

// ---------------------------------------------------------------------------
// GEMM2: out = aout @ w_proj + b_proj  (fp32 output)
__global__ __launch_bounds__(256) void k_gemm_proj(const short* __restrict__ A,
                                                   const short* __restrict__ B,
                                                   const float* __restrict__ bias,
                                                   float* __restrict__ C) {
  __shared__ short As[2 * 8192];
  __shared__ short Bs[2 * 8192];
  f32x4 acc[4][4];
  const int mBase = blockIdx.x * 128, nBase = blockIdx.y * 128;
  mm_loop(A, B, 1024, mBase, nBase, As, Bs, acc);

  const int tid = threadIdx.x;
  const int w = tid >> 6, lane = tid & 63;
  const int wr = w >> 1, wc = w & 1;
  const int lhi = lane >> 4, llo = lane & 15;
#pragma unroll
  for (int mi = 0; mi < 4; mi++)
#pragma unroll
    for (int ni = 0; ni < 4; ni++) {
      const int col = nBase + wc * 64 + ni * 16 + llo;
      const float bv = bias[col];
#pragma unroll
      for (int j = 0; j < 4; j++) {
        const int row = mBase + wr * 64 + mi * 16 + lhi * 4 + j;
        C[(size_t)row * 1024 + col] = acc[mi][ni][j] + bv;
      }
    }
}

// ---------------------------------------------------------------------------
extern "C" void kernel_launch(void* const* d_in, const int* in_sizes, int n_in,
                              void* d_out, int out_size, void* d_ws, size_t ws_size,
                              hipStream_t stream) {
  const float* x      = (const float*)d_in[0];
  const float* w_qkv  = (const float*)d_in[1];
  const float* b_qkv  = (const float*)d_in[2];
  const float* g_q    = (const float*)d_in[3];
  const float* be_q   = (const float*)d_in[4];
  const float* g_k    = (const float*)d_in[5];
  const float* be_k   = (const float*)d_in[6];
  const float* w_proj = (const float*)d_in[7];
  const float* b_proj = (const float*)d_in[8];
  float* out = (float*)d_out;

  char* ws = (char*)d_ws;
  short* xb     = (short*)(ws);                       // 4096x1024      8 MB
  short* wqkvT  = (short*)(ws + ((size_t)8  << 20));  // 3072x1024      6 MB
  short* wprojT = (short*)(ws + ((size_t)14 << 20));  // 1024x1024      2 MB
  short* Qg     = (short*)(ws + ((size_t)16 << 20));  // [32][2048][64] 8 MB
  short* Kg     = (short*)(ws + ((size_t)24 << 20));  // [32][2048][64] 8 MB
  short* Vtg    = (short*)(ws + ((size_t)32 << 20));  // [32][64][2048] 8 MB
  short* aout   = (short*)(ws + ((size_t)40 << 20));  // 4096x1024      8 MB

  k_cvt<<<4096, 256, 0, stream>>>(x, xb, 4096 * 1024);
  k_transpose<<<dim3(3072 / 32, 1024 / 32), dim3(32, 8), 0, stream>>>(w_qkv, wqkvT, 1024, 3072);
  k_transpose<<<dim3(1024 / 32, 1024 / 32), dim3(32, 8), 0, stream>>>(w_proj, wprojT, 1024, 1024);
  k_gemm_qkv<<<dim3(32, 24), 256, 0, stream>>>(xb, wqkvT, b_qkv, g_q, be_q, g_k, be_k, Qg, Kg, Vtg);
  k_attn<<<dim3(32, 32), 256, 0, stream>>>(Qg, Kg, Vtg, aout);
  k_gemm_proj<<<dim3(32, 8), 256, 0, stream>>>(aout, wprojT, b_proj, out);
}

// Round 6
// 218.023 us; speedup vs baseline: 1.4581x; 1.0097x over previous
//
#include <hip/hip_runtime.h>
#include <hip/hip_bf16.h>

// ---------------------------------------------------------------------------
// Fused attention block, bf16 MFMA pipeline.
//   x[2,2048,1024] -> qkv GEMM (+bias, fused per-head LN on q,k) -> flash attn
//   -> proj GEMM (+bias) -> out fp32.
// MFMA 16x16x32 bf16 layouts:
//   A: lane l holds row (l&15), k = 8*(l>>4)+e
//   B: lane l holds col (l&15), k = 8*(l>>4)+e
//   C/D: lane l holds col (l&15), row = (l>>4)*4 + reg
//
// k_attn notes:
//  * No softmax max-tracking: q is LN'd (unit norm after *hd^-0.5), k LN'd
//    (norm 8) => |S| <= 8 (Cauchy-Schwarz), exp(S) <= e^8 ~ 3e3, row sums
//    <= 6e6: fp32/bf16 safe. Row sums via MFMA with ones-B fragment.
//  * Swapped QK^T: mfma(K,Q) gives S^T in C-layout => lane holds 4
//    consecutive k for one q-row => P pair-packed + ds_write_b64.
//  * All paired f32->bf16 conversions via __float22bfloat162_rn (RNE,
//    correct-by-construction; compiler may emit v_cvt_pk_bf16_f32).
//    R4 post-mortem: hand-asm v_cvt_pk_bf16_f32 gave 10x absmax -- do not
//    reintroduce raw asm for this.
//  * K/V/P LDS tiles XOR-swizzled (16B-slot ^ (row&7)); global_load_lds
//    writes linearly so the swizzle is pre-applied on the global source.
//  * 2-phase double-buffered staging with incremented global pointers,
//    one __syncthreads() per K-tile.
// ---------------------------------------------------------------------------

typedef short bf16x8 __attribute__((ext_vector_type(8)));
typedef float f32x4  __attribute__((ext_vector_type(4)));

__device__ __forceinline__ short f2bf(float f) {
  union { float f; unsigned u; } c; c.f = f;
  unsigned r = c.u + 0x7fffu + ((c.u >> 16) & 1u);   // RNE
  return (short)(r >> 16);
}

// pack two f32 -> two bf16 in one u32 (lo = a, hi = b), RNE
__device__ __forceinline__ unsigned pk2(float a, float b) {
  __hip_bfloat162 h = __float22bfloat162_rn(make_float2(a, b));
  unsigned u;
  __builtin_memcpy(&u, &h, 4);
  return u;
}

__device__ __forceinline__ void gld16(const void* g, void* l) {
  __builtin_amdgcn_global_load_lds(
      (const __attribute__((address_space(1))) unsigned int*)(unsigned long long)g,
      (__attribute__((address_space(3))) unsigned int*)(unsigned int)(unsigned long long)l,
      16, 0, 0);
}

// ---------------------------------------------------------------------------
__global__ void k_cvt(const float* __restrict__ in, short* __restrict__ out, int n) {
  int i = (blockIdx.x * blockDim.x + threadIdx.x) * 4;
  if (i < n) {
    float4 f = *(const float4*)(in + i);
    uint2 u;
    u.x = pk2(f.x, f.y);
    u.y = pk2(f.z, f.w);
    *(uint2*)(out + i) = u;
  }
}

__global__ void k_transpose(const float* __restrict__ in, short* __restrict__ out,
                            int R, int C) {
  __shared__ float t[32][33];
  const int tx = threadIdx.x, ty = threadIdx.y;
  const int c0 = blockIdx.x * 32, r0 = blockIdx.y * 32;
#pragma unroll
  for (int i = 0; i < 4; i++)
    t[ty * 4 + i][tx] = in[(size_t)(r0 + ty * 4 + i) * C + c0 + tx];
  __syncthreads();
#pragma unroll
  for (int i = 0; i < 4; i++)
    out[(size_t)(c0 + ty * 4 + i) * R + r0 + tx] = f2bf(t[tx][ty * 4 + i]);
}

// ---------------------------------------------------------------------------
// GEMM mainloop: C128x128 = A[M,K]bf16 @ B[N,K]bf16^T.
// 2-phase double-buffered, pointer-incremented staging.
__device__ __forceinline__ void mm_loop(const short* __restrict__ A,
                                        const short* __restrict__ B,
                                        int K, int mBase, int nBase,
                                        short* As, short* Bs, f32x4 acc[4][4]) {
  const int tid = threadIdx.x;
  const int w = tid >> 6, lane = tid & 63;
  const int wr = w >> 1, wc = w & 1;
  const int lhi = lane >> 4, llo = lane & 15;
  const int rin = lane >> 3;
  const int kin = (lane & 7) * 8;

  const f32x4 fz = {0.f, 0.f, 0.f, 0.f};
#pragma unroll
  for (int mi = 0; mi < 4; mi++)
#pragma unroll
    for (int ni = 0; ni < 4; ni++) acc[mi][ni] = fz;

  const int nkt = K >> 6;

  const short* pA[4];
  const short* pB[4];
#pragma unroll
  for (int i = 0; i < 4; i++) {
    const int row = (w * 4 + i) * 8 + rin;
    pA[i] = A + (size_t)(mBase + row) * K + kin;
    pB[i] = B + (size_t)(nBase + row) * K + kin;
  }

#define MMSTAGE(buf)                                                           \
  {                                                                            \
    _Pragma("unroll")                                                          \
    for (int i = 0; i < 4; i++) {                                              \
      const int c = w * 4 + i;                                                 \
      gld16(pA[i], As + (buf) * 8192 + c * 512);                               \
      gld16(pB[i], Bs + (buf) * 8192 + c * 512);                               \
      pA[i] += 64;                                                             \
      pB[i] += 64;                                                             \
    }                                                                          \
  }

  MMSTAGE(0);
  __syncthreads();
  int cur = 0;

  for (int kb = 0; kb < nkt; kb++) {
    if (kb + 1 < nkt) MMSTAGE(cur ^ 1);
    const short* Ac = As + cur * 8192;
    const short* Bc = Bs + cur * 8192;
#pragma unroll
    for (int kk = 0; kk < 2; kk++) {
      bf16x8 a[4], b[4];
#pragma unroll
      for (int mi = 0; mi < 4; mi++)
        a[mi] = *(const bf16x8*)(Ac + (wr * 64 + mi * 16 + llo) * 64 + kk * 32 + lhi * 8);
#pragma unroll
      for (int ni = 0; ni < 4; ni++)
        b[ni] = *(const bf16x8*)(Bc + (wc * 64 + ni * 16 + llo) * 64 + kk * 32 + lhi * 8);
#pragma unroll
      for (int mi = 0; mi < 4; mi++)
#pragma unroll
        for (int ni = 0; ni < 4; ni++)
          acc[mi][ni] = __builtin_amdgcn_mfma_f32_16x16x32_bf16(a[mi], b[ni], acc[mi][ni], 0, 0, 0);
    }
    __syncthreads();
    cur ^= 1;
  }
#undef MMSTAGE
}

// ---------------------------------------------------------------------------
// GEMM1: qkv = x @ w_qkv + b, fused per-head LN epilogue.
__global__ __launch_bounds__(256) void k_gemm_qkv(
    const short* __restrict__ A, const short* __restrict__ B,
    const float* __restrict__ bqkv,
    const float* __restrict__ g_q, const float* __restrict__ be_q,
    const float* __restrict__ g_k, const float* __restrict__ be_k,
    short* __restrict__ Qg, short* __restrict__ Kg, short* __restrict__ Vtg) {
  __shared__ short As[2 * 8192];
  __shared__ short Bs[2 * 8192];
  f32x4 acc[4][4];
  const int mBase = blockIdx.x * 128, nBase = blockIdx.y * 128;
  mm_loop(A, B, 1024, mBase, nBase, As, Bs, acc);

  const int tid = threadIdx.x;
  const int w = tid >> 6, lane = tid & 63;
  const int wr = w >> 1, wc = w & 1;
  const int lhi = lane >> 4, llo = lane & 15;

  const int cg0 = nBase + wc * 64;
  const int t = cg0 >> 10;               // 0=q 1=k 2=v
  const int h = (cg0 & 1023) >> 6;

  float bias[4], gg[4], bb[4];
#pragma unroll
  for (int ni = 0; ni < 4; ni++) {
    const int d = ni * 16 + llo;
    bias[ni] = bqkv[cg0 + d];
    if (t == 0)      { gg[ni] = g_q[d]; bb[ni] = be_q[d]; }
    else if (t == 1) { gg[ni] = g_k[d]; bb[ni] = be_k[d]; }
    else             { gg[ni] = 1.f;    bb[ni] = 0.f; }
  }

#pragma unroll
  for (int mi = 0; mi < 4; mi++) {
    float v[4][4];
#pragma unroll
    for (int ni = 0; ni < 4; ni++)
#pragma unroll
      for (int j = 0; j < 4; j++) v[ni][j] = acc[mi][ni][j] + bias[ni];

    if (t < 2) {
#pragma unroll
      for (int j = 0; j < 4; j++) {
        float s = 0.f, s2 = 0.f;
#pragma unroll
        for (int ni = 0; ni < 4; ni++) { s += v[ni][j]; s2 += v[ni][j] * v[ni][j]; }
#pragma unroll
        for (int msk = 1; msk < 16; msk <<= 1) {
          s  += __shfl_xor(s,  msk, 64);
          s2 += __shfl_xor(s2, msk, 64);
        }
        const float mu = s * 0.015625f;
        const float var = s2 * 0.015625f - mu * mu;
        const float rs = rsqrtf(var + 1e-5f);
#pragma unroll
        for (int ni = 0; ni < 4; ni++) {
          float y = (v[ni][j] - mu) * rs * gg[ni] + bb[ni];
          if (t == 0) y *= 0.125f;       // hd^-0.5
          v[ni][j] = y;
        }
      }
    }
    const int rbase = mBase + wr * 64 + mi * 16 + lhi * 4;
#pragma unroll
    for (int j = 0; j < 4; j++) {
      const int r = rbase + j;
      const int b_ = r >> 11;
      const int n = r & 2047;
      const int bh = b_ * 16 + h;
#pragma unroll
      for (int np = 0; np < 2; np++) {           // ni pairs (0,1) and (2,3)
        const int d0 = np * 32 + llo;
        const unsigned u = pk2(v[np * 2][j], v[np * 2 + 1][j]);
        const short lo = (short)(u & 0xffffu);
        const short hi = (short)(u >> 16);
        if (t == 0) {
          Qg[((size_t)bh * 2048 + n) * 64 + d0]      = lo;
          Qg[((size_t)bh * 2048 + n) * 64 + d0 + 16] = hi;
        } else if (t == 1) {
          Kg[((size_t)bh * 2048 + n) * 64 + d0]      = lo;
          Kg[((size_t)bh * 2048 + n) * 64 + d0 + 16] = hi;
        } else {
          Vtg[((size_t)bh * 64 + d0) * 2048 + n]        = lo;
          Vtg[((size_t)bh * 64 + d0 + 16) * 2048 + n]   = hi;
        }
      }
    }
  }
}

// ---------------------------------------------------------------------------
// Flash attention: swapped QK^T, no-max softmax (__expf), packed b64 P-store,
// swizzled LDS, 2-phase dbuf staging (pointer-incremented), setprio.
__global__ __launch_bounds__(256) void k_attn(const short* __restrict__ Qg,
                                              const short* __restrict__ Kg,
                                              const short* __restrict__ Vtg,
                                              short* __restrict__ aout) {
  __shared__ short KV[2][8192];     // [buf][ K: 0..4095 | V: 4096..8191 ]
  __shared__ short Ps[4][1024];     // per-wave [16 q][64 k], swizzled
  const int tid = threadIdx.x;
  const int w = tid >> 6, lane = tid & 63;
  const int lhi = lane >> 4, llo = lane & 15;
  const int rin = lane >> 3;               // 0..7: row within 8-row chunk
  const int tg = (lane & 7) ^ rin;         // pre-swizzled 16B slot in source
  const int bh = blockIdx.y;
  const int qrow0 = blockIdx.x * 64 + w * 16;

  const short* Qrow = Qg + ((size_t)bh * 2048 + qrow0 + llo) * 64;
  const bf16x8 qa0 = *(const bf16x8*)(Qrow + lhi * 8);
  const bf16x8 qa1 = *(const bf16x8*)(Qrow + 32 + lhi * 8);

  bf16x8 onesb;
#pragma unroll
  for (int e = 0; e < 8; e++) onesb[e] = (short)0x3F80;   // bf16 1.0

  const f32x4 fz = {0.f, 0.f, 0.f, 0.f};
  f32x4 o[4];
#pragma unroll
  for (int dg = 0; dg < 4; dg++) o[dg] = fz;
  f32x4 lsum = fz;

  short* Pw = Ps[w];
  const size_t kbase = (size_t)bh * 2048;
  const size_t vbase = (size_t)bh * 64;

  // staging pointers: waves 0,1 load K chunks (advance 64 rows * 64 = 4096),
  // waves 2,3 load V^T chunks (advance 64 cols = 64).
  const short* gp[4];
#pragma unroll
  for (int i = 0; i < 4; i++) {
    const int cc = w * 4 + i;
    gp[i] = (cc < 8)
        ? (Kg  + (kbase + (size_t)(cc * 8 + rin)) * 64 + tg * 8)
        : (Vtg + (vbase + (size_t)((cc - 8) * 8 + rin)) * 2048 + tg * 8);
  }
  const int gstride = (w < 2) ? 4096 : 64;

#define STAGE(buf)                                                             \
  {                                                                            \
    _Pragma("unroll")                                                          \
    for (int i = 0; i < 4; i++) {                                              \
      gld16(gp[i], &KV[buf][(w * 4 + i) * 512]);                               \
      gp[i] += gstride;                                                        \
    }                                                                          \
  }

  STAGE(0);
  __syncthreads();
  int cur = 0;

  for (int kt = 0; kt < 32; kt++) {
    if (kt < 31) STAGE(cur ^ 1);

    const short* Kc = KV[cur];
    const short* Vc = KV[cur] + 4096;

    // S^T[64 k x 16 q] = K @ Q^T  (swapped operands; frag layouts identical)
    // => lane holds S[q=llo][k = krg*16 + lhi*4 + j]
    f32x4 s[4];
    __builtin_amdgcn_s_setprio(1);
#pragma unroll
    for (int krg = 0; krg < 4; krg++) {
      const int rk = krg * 16 + llo;
      const int sw = rk & 7;
      const bf16x8 kb0 = *(const bf16x8*)(Kc + rk * 64 + ((lhi ^ sw)) * 8);
      const bf16x8 kb1 = *(const bf16x8*)(Kc + rk * 64 + (((4 + lhi) ^ sw)) * 8);
      f32x4 z = fz;
      z = __builtin_amdgcn_mfma_f32_16x16x32_bf16(kb0, qa0, z, 0, 0, 0);
      z = __builtin_amdgcn_mfma_f32_16x16x32_bf16(kb1, qa1, z, 0, 0, 0);
      s[krg] = z;
    }
    __builtin_amdgcn_s_setprio(0);

    // P = exp(S); pack 4 consecutive-k bf16 (RNE pk2), ds_write_b64 per krg.
#pragma unroll
    for (int krg = 0; krg < 4; krg++) {
      const float p0 = __expf(s[krg][0]);
      const float p1 = __expf(s[krg][1]);
      const float p2 = __expf(s[krg][2]);
      const float p3 = __expf(s[krg][3]);
      uint2 u;
      u.x = pk2(p0, p1);
      u.y = pk2(p2, p3);
      // byte addr: row llo, k = krg*16 + lhi*4 ; slot = k>>3, swizzled
      char* pb = (char*)Pw + llo * 128 +
                 (((krg * 2 + (lhi >> 1)) ^ (llo & 7)) << 4) + ((lhi & 1) << 3);
      *(uint2*)pb = u;
    }

    // P fragments (A-layout): row=llo, swizzle-read
    const int swp = llo & 7;
    const bf16x8 pa0 = *(const bf16x8*)(Pw + llo * 64 + ((lhi ^ swp)) * 8);
    const bf16x8 pa1 = *(const bf16x8*)(Pw + llo * 64 + (((4 + lhi) ^ swp)) * 8);

    __builtin_amdgcn_s_setprio(1);
    // row sums via MFMA with ones-B (each col of C gets the full row sum)
    lsum = __builtin_amdgcn_mfma_f32_16x16x32_bf16(pa0, onesb, lsum, 0, 0, 0);
    lsum = __builtin_amdgcn_mfma_f32_16x16x32_bf16(pa1, onesb, lsum, 0, 0, 0);

    // O += P @ V   (V^T tile, swizzle-read)
#pragma unroll
    for (int dg = 0; dg < 4; dg++) {
      const int rv = dg * 16 + llo;
      const int swv = rv & 7;
      const bf16x8 vb0 = *(const bf16x8*)(Vc + rv * 64 + ((lhi ^ swv)) * 8);
      const bf16x8 vb1 = *(const bf16x8*)(Vc + rv * 64 + (((4 + lhi) ^ swv)) * 8);
      o[dg] = __builtin_amdgcn_mfma_f32_16x16x32_bf16(pa0, vb0, o[dg], 0, 0, 0);
      o[dg] = __builtin_amdgcn_mfma_f32_16x16x32_bf16(pa1, vb1, o[dg], 0, 0, 0);
    }
    __builtin_amdgcn_s_setprio(0);
    __syncthreads();
    cur ^= 1;
  }
#undef STAGE

  const int b_ = bh >> 4, h = bh & 15;
#pragma unroll
  for (int j = 0; j < 4; j++) {
    const float inv = 1.f / lsum[j];
    const int n = qrow0 + lhi * 4 + j;
    short* arow = aout + ((size_t)(b_ * 2048 + n)) * 1024 + h * 64 + llo;
#pragma unroll
    for (int dp = 0; dp < 2; dp++) {            // dg pairs (0,1), (2,3)
      const unsigned u = pk2(o[dp * 2][j] * inv, o[dp * 2 + 1][j] * inv);
      arow[dp * 32]      = (short)(u & 0xffffu);
      arow[dp * 32 + 16] = (short)(u >> 16);
    }
  }
}

// ---------------------------------------------------------------------------
// GEMM2: out = aout @ w_proj + b_proj  (fp32 output)
__global__ __launch_bounds__(256) void k_gemm_proj(const short* __restrict__ A,
                                                   const short* __restrict__ B,
                                                   const float* __restrict__ bias,
                                                   float* __restrict__ C) {
  __shared__ short As[2 * 8192];
  __shared__ short Bs[2 * 8192];
  f32x4 acc[4][4];
  const int mBase = blockIdx.x * 128, nBase = blockIdx.y * 128;
  mm_loop(A, B, 1024, mBase, nBase, As, Bs, acc);

  const int tid = threadIdx.x;
  const int w = tid >> 6, lane = tid & 63;
  const int wr = w >> 1, wc = w & 1;
  const int lhi = lane >> 4, llo = lane & 15;
#pragma unroll
  for (int mi = 0; mi < 4; mi++)
#pragma unroll
    for (int ni = 0; ni < 4; ni++) {
      const int col = nBase + wc * 64 + ni * 16 + llo;
      const float bv = bias[col];
#pragma unroll
      for (int j = 0; j < 4; j++) {
        const int row = mBase + wr * 64 + mi * 16 + lhi * 4 + j;
        C[(size_t)row * 1024 + col] = acc[mi][ni][j] + bv;
      }
    }
}

// ---------------------------------------------------------------------------
extern "C" void kernel_launch(void* const* d_in, const int* in_sizes, int n_in,
                              void* d_out, int out_size, void* d_ws, size_t ws_size,
                              hipStream_t stream) {
  const float* x      = (const float*)d_in[0];
  const float* w_qkv  = (const float*)d_in[1];
  const float* b_qkv  = (const float*)d_in[2];
  const float* g_q    = (const float*)d_in[3];
  const float* be_q   = (const float*)d_in[4];
  const float* g_k    = (const float*)d_in[5];
  const float* be_k   = (const float*)d_in[6];
  const float* w_proj = (const float*)d_in[7];
  const float* b_proj = (const float*)d_in[8];
  float* out = (float*)d_out;

  char* ws = (char*)d_ws;
  short* xb     = (short*)(ws);                       // 4096x1024      8 MB
  short* wqkvT  = (short*)(ws + ((size_t)8  << 20));  // 3072x1024      6 MB
  short* wprojT = (short*)(ws + ((size_t)14 << 20));  // 1024x1024      2 MB
  short* Qg     = (short*)(ws + ((size_t)16 << 20));  // [32][2048][64] 8 MB
  short* Kg     = (short*)(ws + ((size_t)24 << 20));  // [32][2048][64] 8 MB
  short* Vtg    = (short*)(ws + ((size_t)32 << 20));  // [32][64][2048] 8 MB
  short* aout   = (short*)(ws + ((size_t)40 << 20));  // 4096x1024      8 MB

  k_cvt<<<4096, 256, 0, stream>>>(x, xb, 4096 * 1024);
  k_transpose<<<dim3(3072 / 32, 1024 / 32), dim3(32, 8), 0, stream>>>(w_qkv, wqkvT, 1024, 3072);
  k_transpose<<<dim3(1024 / 32, 1024 / 32), dim3(32, 8), 0, stream>>>(w_proj, wprojT, 1024, 1024);
  k_gemm_qkv<<<dim3(32, 24), 256, 0, stream>>>(xb, wqkvT, b_qkv, g_q, be_q, g_k, be_k, Qg, Kg, Vtg);
  k_attn<<<dim3(32, 32), 256, 0, stream>>>(Qg, Kg, Vtg, aout);
  k_gemm_proj<<<dim3(32, 8), 256, 0, stream>>>(aout, wprojT, b_proj, out);
}